// Round 13
// baseline (163.812 us; speedup 1.0000x reference)
//
#include <hip/hip_runtime.h>
#include <math.h>

// R16: R12 base (best measured 157.3us; R15's BAR_RAW tile-top tweak reverted) +
// ONE k_moe change: drop the Bu2 LDS buffer. W2 B-fragments are loaded DIRECTLY
// from L2 in MFMA-ready layout within the same hc iteration (4 quads/row share a
// 64B line; load->use distance = GEMM1+gelu+2 barriers ~400cyc covers L2 latency;
// no cross-iteration register residency -> no R11 rematerialization hazard).
// Effect: LDS 49.6KB -> 31.0KB -> 5 blocks/CU -> all 1032 tiles co-resident
// (grid 1032, tile-stride loop removed) -- eliminates the 2-round serialization
// that R12's tile-stride forced (264 blocks ran 2 tiles while 504 idled).
// W1 keeps R12's proven ds_write-anchored wave-private prefetch staging.
// Pipeline: memset(3KB) -> k_prep_tr(1792) -> k_embed(256) -> k_moe(1032)
// -> k_flat(256) -> k_head(256) -> k_final(96)

typedef __attribute__((ext_vector_type(8))) short bf16x8;
typedef __attribute__((ext_vector_type(4))) float f32x4;

__device__ __forceinline__ float bf2f(unsigned short u){
  unsigned x = ((unsigned)u) << 16; float f; __builtin_memcpy(&f, &x, 4); return f;
}
__device__ __forceinline__ unsigned short f2bf(float f){
  unsigned x; __builtin_memcpy(&x, &f, 4);
  return (unsigned short)((x + 0x7FFFu + ((x >> 16) & 1u)) >> 16);
}
__device__ __forceinline__ float ldin(const void* p, int i, int f32){
  return f32 ? ((const float*)p)[i] : bf2f(((const unsigned short*)p)[i]);
}
__device__ __forceinline__ void stout(void* p, int i, float v, int f32){
  if (f32) ((float*)p)[i] = v; else ((unsigned short*)p)[i] = f2bf(v);
}
__device__ __forceinline__ f32x4 mfma16(bf16x8 a, bf16x8 b, f32x4 c){
  return __builtin_amdgcn_mfma_f32_16x16x32_bf16(a, b, c, 0, 0, 0);
}
// raw barrier: waits only LDS ops, leaves global loads in flight (vs __syncthreads)
#define BAR_RAW() asm volatile("s_waitcnt lgkmcnt(0)\n\ts_barrier" ::: "memory")
// tanh-form gelu: x * sigmoid(1.5957691216*(x + 0.044715 x^3)); |dev vs erf-gelu| <~3e-4
__device__ __forceinline__ float gelu_fast(float v){
  float u = v*v;
  float inner = v * fmaf(0.044715f, u, 1.0f);
  float e = __expf(-1.5957691216f * inner);
  return v / (1.0f + e);     // v * sigmoid; e=inf -> 0, e=0 -> v  (no NaN)
}

// ---- ws layout (~82 MB of the 256 MiB workspace) ----
#define OFF_SUMS   64
#define OFF_MEANS  256
#define OFF_STDS   1280
#define OFF_ECNT   2304        // 8 expert counters @ 128B stride (ecnt[e*32]); memset 0..3328
#define OFF_W1T    134400      // 8*512*128 bf16
#define OFF_W2T    1182976     // 8*128*512 bf16
#define OFF_WHT    2231552     // 96*8192 bf16
#define OFF_CW     3804416     // 16384*8 f32
#define OFF_XFBF   4328704     // 16384*128 bf16
#define OFF_FLATB  8523008     // 256*8192 bf16; elist (8*16384 int) overlays until k_flat
#define OFF_EO     12717312    // 8*16384 slots x 128 f32 = 64MB (sparse-used, no memset)
#define OFF_TOKSLOT 79826176   // 16384 x 2 int
#define OFF_DECP   79957248    // 16 x 24576 f32 partials (fully written by k_head)
// end ~81.5MB

// ========== K1: tiled weight transposes ==========
__global__ __launch_bounds__(256) void k_prep_tr(const void* __restrict__ W1,
                                                 const void* __restrict__ W2,
                                                 const void* __restrict__ Wh,
                                                 int f32,
                                                 unsigned short* W1T, unsigned short* W2T,
                                                 unsigned short* WhT){
  int t = threadIdx.x;
  __shared__ float tile[32*33];
  int tb = blockIdx.x;
  int r = t >> 3, cg = (t & 7) * 4;
  const void* src; unsigned short* dst;
  int in0, instride, out0, outstride;
  if (tb < 512){            // W1 [e][d 128][h 512] -> W1T [e][h][d]
    int e = tb >> 6, ti = tb & 63, d0 = (ti & 3) * 32, h0 = (ti >> 2) * 32;
    src = W1; dst = W1T;
    in0 = e*65536 + d0*512 + h0; instride = 512;
    out0 = e*65536 + h0*128 + d0; outstride = 128;
  } else if (tb < 1024){    // W2 [e][h 512][d 128] -> W2T [e][d][h]
    int tc = tb - 512;
    int e = tc >> 6, ti = tc & 63, d0 = (ti & 3) * 32, h0 = (ti >> 2) * 32;
    src = W2; dst = W2T;
    in0 = e*65536 + h0*128 + d0; instride = 128;
    out0 = e*65536 + d0*512 + h0; outstride = 512;
  } else {                  // Wh [k 8192][n 96] -> WhT [n][k]
    int tc = tb - 1024;
    int kt = tc / 3, nt = tc - kt*3;
    int k0 = kt*32, n0 = nt*32;
    src = Wh; dst = WhT;
    in0 = k0*96 + n0; instride = 96;
    out0 = n0*8192 + k0; outstride = 8192;
  }
  #pragma unroll
  for (int j = 0; j < 4; ++j)
    tile[r*33 + cg + j] = ldin(src, in0 + r*instride + cg + j, f32);
  __syncthreads();
  ushort4 o;
  o.x = f2bf(tile[(cg+0)*33 + r]);
  o.y = f2bf(tile[(cg+1)*33 + r]);
  o.z = f2bf(tile[(cg+2)*33 + r]);
  o.w = f2bf(tile[(cg+3)*33 + r]);
  *(ushort4*)(dst + out0 + r*outstride + cg) = o;
}

// ========== K2: per-bv stats + patch embed + inline PE + gating + aux + routing ==========
__global__ __launch_bounds__(256) void k_embed(const void* __restrict__ xe,
                                               const void* __restrict__ Wp,
                                               const void* __restrict__ Wg,
                                               int f32,
                                               float* means, float* stds,
                                               unsigned short* xfbf, float* cwg,
                                               float* sums,
                                               int* ecnt, int* elist, int* tokslot){
  __shared__ float xn[512];
  __shared__ float WpL[2048];
  __shared__ float WgL[1024];
  __shared__ float Xf[8192];
  __shared__ float lp[1024];
  __shared__ float taux[576];
  __shared__ float reds[256], redss[256];
  __shared__ float msh[2];
  __shared__ int lcnt[8], lbase[8];

  int bv = blockIdx.x;
  int b = bv >> 5, v = bv & 31;
  int t = threadIdx.x;

  if (t < 8) lcnt[t] = 0;

  float x0 = ldin(xe, (b*512 + t)*32 + v, f32);
  float x1 = ldin(xe, (b*512 + t + 256)*32 + v, f32);
  xn[t] = x0; xn[t+256] = x1;
  reds[t] = x0 + x1; redss[t] = x0*x0 + x1*x1;
  #pragma unroll
  for (int it = 0; it < 8; ++it)
    WpL[it*256 + t] = ldin(Wp, it*256 + t, f32);
  #pragma unroll
  for (int j = 0; j < 4; ++j)
    WgL[j*256 + t] = ldin(Wg, j*256 + t, f32);
  __syncthreads();
  for (int s = 128; s > 0; s >>= 1){
    if (t < s){ reds[t] += reds[t+s]; redss[t] += redss[t+s]; }
    __syncthreads();
  }
  if (t == 0){
    float m = reds[0] / 512.f;
    float sd = sqrtf(redss[0] / 512.f - m*m + 1e-5f);
    msh[0] = m; msh[1] = 1.f / sd;
    means[bv] = m; stds[bv] = sd;
  }
  __syncthreads();
  float mean = msh[0], rstd = msh[1];
  xn[t] = (xn[t] - mean) * rstd;
  xn[t+256] = (xn[t+256] - mean) * rstd;
  __syncthreads();
  {
    int p = t >> 2, q = t & 3;
    float tv[16];
    #pragma unroll
    for (int l = 0; l < 16; ++l){
      int xi = p*8 + l; if (xi > 511) xi = 511;   // edge pad
      tv[l] = xn[xi];
    }
    for (int dd = 0; dd < 32; ++dd){
      int d = q*32 + dd;
      // inline PE (bit-identical expression to the old precomputed table; verified R13/R14)
      float freq = __expf(-(float)(d & ~1) * 0.07195578415606394f);
      float ang = (float)p * freq;
      float acc = (d & 1) ? __cosf(ang) : __sinf(ang);
      #pragma unroll
      for (int l = 0; l < 16; ++l) acc += tv[l] * WpL[l*128 + d];
      Xf[p*128 + d] = acc;
    }
  }
  __syncthreads();
  if (t < 128){
    int p = t >> 1, half = t & 1;
    float s[8] = {0,0,0,0,0,0,0,0};
    for (int d = half*64; d < half*64 + 64; ++d){
      float xv = Xf[p*128 + d];
      #pragma unroll
      for (int e = 0; e < 8; ++e) s[e] += xv * WgL[d*8 + e];
    }
    #pragma unroll
    for (int e = 0; e < 8; ++e) lp[(p*2 + half)*8 + e] = s[e];
  }
  __syncthreads();
  int bi = 0, si = 0, lo0 = 0, lo1 = 0;
  if (t < 64){
    int p = t;
    float lg[8];
    #pragma unroll
    for (int e = 0; e < 8; ++e) lg[e] = lp[(p*2)*8 + e] + lp[(p*2+1)*8 + e];
    float m = lg[0];
    #pragma unroll
    for (int e = 1; e < 8; ++e) m = fmaxf(m, lg[e]);
    float pr[8]; float se = 0.f;
    #pragma unroll
    for (int e = 0; e < 8; ++e){ pr[e] = __expf(lg[e] - m); se += pr[e]; }
    float inv = 1.f / se;
    float lse = m + logf(se);
    #pragma unroll
    for (int e = 0; e < 8; ++e) pr[e] *= inv;
    float best = -1.f;
    #pragma unroll
    for (int e = 0; e < 8; ++e) if (pr[e] > best){ best = pr[e]; bi = e; }
    float sec = -1.f;
    #pragma unroll
    for (int e = 0; e < 8; ++e) if (e != bi && pr[e] > sec){ sec = pr[e]; si = e; }
    #pragma unroll
    for (int e = 0; e < 8; ++e){
      float w = (e == bi) ? best : ((e == si) ? sec : 0.f);
      cwg[(bv*64 + p)*8 + e] = w;
      taux[p*9 + e] = pr[e];
    }
    taux[p*9 + 8] = lse * lse;
    lp[p] = (float)bi; lp[64 + p] = (float)si;   // reuse lp for mask info
    // --- routing: fast LDS atomics give local offsets (order-free) ---
    lo0 = atomicAdd(&lcnt[bi], 1);
    lo1 = atomicAdd(&lcnt[si], 1);
  }
  __syncthreads();
  // one global atomic per (block, expert); counters 128B apart -> parallel lines
  if (t < 8) lbase[t] = atomicAdd(ecnt + t*32, lcnt[t]);
  __syncthreads();
  if (t < 64){
    int n = bv*64 + t;
    int p0 = lbase[bi] + lo0, p1 = lbase[si] + lo1;
    elist[bi*16384 + p0] = n;
    elist[si*16384 + p1] = n;
    tokslot[n*2]     = (bi << 14) + p0;    // slot = e*16384 + pos
    tokslot[n*2 + 1] = (si << 14) + p1;
  }
  if (t < 17){
    float s = 0.f;
    if (t < 8){ for (int p = 0; p < 64; ++p) s += taux[p*9 + t]; }
    else if (t < 16){
      int e = t - 8;
      for (int p = 0; p < 64; ++p)
        s += ((int)lp[p] == e || (int)lp[64+p] == e) ? 1.f : 0.f;
    }
    else { for (int p = 0; p < 64; ++p) s += taux[p*9 + 8]; }
    atomicAdd(sums + t, s);
  }
  // Xf -> bf16 xfbf (coalesced b128)
  #pragma unroll
  for (int pass = 0; pass < 4; ++pass){
    int idx = pass*256 + t;         // 1024 groups of 8
    int base = idx*8;
    bf16x8 o;
    #pragma unroll
    for (int j = 0; j < 8; ++j) o[j] = (short)f2bf(Xf[base + j]);
    *(bf16x8*)(xfbf + bv*8192 + base) = o;
  }
}

// ========== K3: routed top-2 FFN; W1 LDS-staged, W2 direct-L2, 5 blocks/CU ==========
// grid = 1032 >= sum_e ceil(cnt[e]/32); all tiles co-resident (5 blocks/CU @31KB).
__global__ __launch_bounds__(256, 5) void k_moe(const unsigned short* __restrict__ xfbf,
                                                const unsigned short* __restrict__ W1T,
                                                const unsigned short* __restrict__ W2T,
                                                const void* __restrict__ b1g,
                                                int f32,
                                                const float* __restrict__ cwg,
                                                const int* __restrict__ ecnt,
                                                const int* __restrict__ elist,
                                                float* __restrict__ Eo){
  __shared__ __align__(16) char lds[31104];
  short* Xs  = (short*)(lds);            // [32][136] gathered tokens  (8704B)
  short* Bu1 = (short*)(lds + 8704);     // [64][136]: wave w owns rows [16w,16w+16)
  short* Ag  = (short*)(lds + 26112);    // [32][72] gelu out (cross-wave) (4608B)
  float* cws = (float*)(lds + 30720);    // [32]
  int*   lsn = (int*)(lds + 30848);      // [32] routed token ids

  int t = threadIdx.x;
  // map block -> (expert e, tile ti) via redundant prefix over 8 counters
  int e = 8, ti = 0;
  {
    int acc = 0, bk = blockIdx.x;
    #pragma unroll
    for (int ee = 0; ee < 8; ++ee){
      int tl = (ecnt[ee*32] + 31) >> 5;
      if (e == 8 && bk < acc + tl){ e = ee; ti = bk - acc; }
      acc += tl;
    }
  }
  if (e == 8) return;                    // beyond total tiles (block-uniform)
  int cntE = ecnt[e*32];
  int tbase = ti*32;

  int wave = t >> 6, lane = t & 63;
  int quad = lane >> 4, li = lane & 15;
  int c1 = wave * 16;                    // GEMM1 column (h) slice per wave
  int c2 = wave * 32;                    // GEMM2 column (d) slice per wave

  const unsigned short* W1e = W1T + e*65536;
  const unsigned short* W2e = W2T + e*65536;

  // ---- issue hc=0 wave-private W1 loads first (fly under routing+gather)
  bf16x8 pf1[4];
  #pragma unroll
  for (int pass = 0; pass < 4; ++pass){
    int idx = pass*64 + lane;
    int row = idx >> 4, kg = idx & 15;   // 16 rows x 16 kg
    pf1[pass] = *(const bf16x8*)(W1e + (c1 + row)*128 + kg*8);
  }

  if (t < 32){
    int ok = (tbase + t) < cntE;
    int n = ok ? elist[e*16384 + tbase + t] : 0;
    lsn[t] = n;
    cws[t] = ok ? cwg[n*8 + e] : 0.f;    // cw=0 pads -> zero contribution
  }
  __syncthreads();                       // R12 semantics (proven)
  // gather 32 token rows (512 x b128)
  #pragma unroll
  for (int pass = 0; pass < 2; ++pass){
    int idx = pass*256 + t;
    int row = idx >> 4, kg = idx & 15;
    int n = lsn[row];
    *(bf16x8*)(Xs + row*136 + kg*8) =
      *(const bf16x8*)(xfbf + n*128 + kg*8);
  }
  // per-lane gate weights for the 8 rows this lane touches
  float cwv[2][4];
  #pragma unroll
  for (int rt = 0; rt < 2; ++rt)
    #pragma unroll
    for (int r = 0; r < 4; ++r)
      cwv[rt][r] = cws[rt*16 + quad*4 + r];
  __syncthreads();                       // Xs visible

  f32x4 Yacc[2][2];
  #pragma unroll
  for (int a = 0; a < 2; ++a)
    #pragma unroll
    for (int bb = 0; bb < 2; ++bb){ f32x4 z = {0.f,0.f,0.f,0.f}; Yacc[a][bb] = z; }

  for (int hc = 0; hc < 8; ++hc){
    // 1. stage own W1 slice from pf regs (same-wave RAW -> lgkmcnt only)
    #pragma unroll
    for (int pass = 0; pass < 4; ++pass){
      int idx = pass*64 + lane;
      int row = idx >> 4, kg = idx & 15;
      *(bf16x8*)(Bu1 + (c1 + row)*136 + kg*8) = pf1[pass];
    }
    // 2. bias for current hc
    float bias = ldin(b1g, e*512 + hc*64 + c1 + li, f32);
    // 3. W2 B-fragments for CURRENT hc, direct from L2 in MFMA layout.
    //    Used at step 8 -- GEMM1 + gelu + 2 barriers (~400cyc) cover L2 latency.
    bf16x8 w2f[2][2];
    #pragma unroll
    for (int ks = 0; ks < 2; ++ks)
      #pragma unroll
      for (int ct = 0; ct < 2; ++ct)
        w2f[ks][ct] = *(const bf16x8*)(W2e + (c2 + ct*16 + li)*512 + hc*64 + ks*32 + quad*8);
    // 4. next chunk's W1 (stays in flight across raw barriers)
    if (hc < 7){
      #pragma unroll
      for (int pass = 0; pass < 4; ++pass){
        int idx = pass*64 + lane;
        int row = idx >> 4, kg = idx & 15;
        pf1[pass] = *(const bf16x8*)(W1e + ((hc+1)*64 + c1 + row)*128 + kg*8);
      }
    }
    // 5. GEMM1: 32 tok x 16 h per wave, K=128 (own Bu1 slice)
    f32x4 acc1[2];
    { f32x4 z = {0.f,0.f,0.f,0.f}; acc1[0] = z; acc1[1] = z; }
    #pragma unroll
    for (int ks = 0; ks < 4; ++ks){
      int kk = ks*32 + quad*8;
      bf16x8 a0 = *(const bf16x8*)(Xs + li*136 + kk);
      bf16x8 a1 = *(const bf16x8*)(Xs + (16 + li)*136 + kk);
      bf16x8 b0 = *(const bf16x8*)(Bu1 + (c1 + li)*136 + kk);
      acc1[0] = mfma16(a0, b0, acc1[0]);
      acc1[1] = mfma16(a1, b0, acc1[1]);
    }
    // 6. barrier A: all waves' prev-iter Ag reads retired (LDS-only wait)
    BAR_RAW();
    // 7. gelu -> Ag (own cols, all rows)
    #pragma unroll
    for (int rt = 0; rt < 2; ++rt){
      #pragma unroll
      for (int r = 0; r < 4; ++r){
        int row = rt*16 + quad*4 + r;
        float g = gelu_fast(acc1[rt][r] + bias);
        Ag[row*72 + c1 + li] = (short)f2bf(g * cwv[rt][r]);
      }
    }
    // 8. barrier B: Ag writes visible (vmcnt untouched -> W1-next/W2 in flight)
    BAR_RAW();
    // 9. GEMM2: 32 tok x 32 d per wave, K=64 (Ag all cols + w2f regs)
    #pragma unroll
    for (int ks = 0; ks < 2; ++ks){
      int kk = ks*32 + quad*8;
      bf16x8 a0 = *(const bf16x8*)(Ag + li*72 + kk);
      bf16x8 a1 = *(const bf16x8*)(Ag + (16 + li)*72 + kk);
      Yacc[0][0] = mfma16(a0, w2f[ks][0], Yacc[0][0]);
      Yacc[0][1] = mfma16(a0, w2f[ks][1], Yacc[0][1]);
      Yacc[1][0] = mfma16(a1, w2f[ks][0], Yacc[1][0]);
      Yacc[1][1] = mfma16(a1, w2f[ks][1], Yacc[1][1]);
    }
  }
  // epilogue: plain stores to this pair's private slot rows (no atomics)
  #pragma unroll
  for (int ct = 0; ct < 2; ++ct){
    int col = c2 + ct*16 + li;
    #pragma unroll
    for (int rt = 0; rt < 2; ++rt)
      #pragma unroll
      for (int r = 0; r < 4; ++r){
        int row = rt*16 + quad*4 + r;
        if (tbase + row < cntE)
          Eo[(size_t)((e << 14) + tbase + row)*128 + col] = Yacc[rt][ct][r];
      }
  }
}

// ========== K4: Eo slot gather-add + sum_e cw*b2 -> flat bf16 [bv][d*64+p] ==========
__global__ __launch_bounds__(256) void k_flat(const float* __restrict__ Eo,
                                              const int* __restrict__ tokslot,
                                              const float* __restrict__ cwg,
                                              const void* __restrict__ b2g,
                                              int f32,
                                              unsigned short* __restrict__ flatb){
  __shared__ float Yl[64*130];
  __shared__ float b2f[1024];
  __shared__ float cwl[512];
  __shared__ int tsl[128];
  int bv = blockIdx.x;
  int t = threadIdx.x;
  if (t < 64){
    int2 v = *(const int2*)(tokslot + (bv*64 + t)*2);
    tsl[t*2] = v.x; tsl[t*2+1] = v.y;
  }
  #pragma unroll
  for (int j = 0; j < 4; ++j) b2f[j*256 + t] = ldin(b2g, j*256 + t, f32);
  #pragma unroll
  for (int j = 0; j < 2; ++j) cwl[j*256 + t] = cwg[bv*512 + j*256 + t];
  __syncthreads();
  #pragma unroll
  for (int pass = 0; pass < 32; ++pass){
    int idx = pass*256 + t;
    int row = idx >> 7, col = idx & 127;
    Yl[row*130 + col] = Eo[(size_t)tsl[row*2]*128 + col]
                      + Eo[(size_t)tsl[row*2+1]*128 + col];
  }
  __syncthreads();
  int d = t >> 1, ph = (t & 1) * 32;
  float b2c[8];
  #pragma unroll
  for (int e = 0; e < 8; ++e) b2c[e] = b2f[e*128 + d];
  unsigned short ob[32];
  for (int j = 0; j < 32; ++j){
    int p = ph + j;
    float add = 0.f;
    #pragma unroll
    for (int e = 0; e < 8; ++e) add += cwl[p*8 + e] * b2c[e];
    ob[j] = f2bf(Yl[p*130 + d] + add);
  }
  #pragma unroll
  for (int m = 0; m < 4; ++m)
    *(bf16x8*)(flatb + bv*8192 + d*64 + ph + m*8) = *(bf16x8*)(ob + m*8);
}

// ========== K5: head GEMM (M=256, N=96, K=8192; K-split 16, partial stores) ==========
__global__ __launch_bounds__(256) void k_head(const unsigned short* __restrict__ flatb,
                                              const unsigned short* __restrict__ WhT,
                                              float* __restrict__ dec_part){
  int t = threadIdx.x;
  int mt = blockIdx.x & 15, kc = blockIdx.x >> 4;
  int wave = t >> 6, lane = t & 63, quad = lane >> 4, li = lane & 15;
  int kbase = kc*512 + wave*128;
  f32x4 acc[6];
  #pragma unroll
  for (int nt = 0; nt < 6; ++nt){ f32x4 z = {0.f,0.f,0.f,0.f}; acc[nt] = z; }
  #pragma unroll
  for (int ks = 0; ks < 4; ++ks){
    int k = kbase + ks*32 + quad*8;
    bf16x8 a = *(const bf16x8*)(flatb + (mt*16 + li)*8192 + k);
    #pragma unroll
    for (int nt = 0; nt < 6; ++nt){
      bf16x8 b = *(const bf16x8*)(WhT + (nt*16 + li)*8192 + k);
      acc[nt] = mfma16(a, b, acc[nt]);
    }
  }
  __shared__ float redsh[4][16][96];
  #pragma unroll
  for (int nt = 0; nt < 6; ++nt)
    #pragma unroll
    for (int r = 0; r < 4; ++r)
      redsh[wave][quad*4 + r][nt*16 + li] = acc[nt][r];
  __syncthreads();
  #pragma unroll
  for (int u = 0; u < 6; ++u){
    int o = t*6 + u;
    int row = o / 96, col = o % 96;
    float s = redsh[0][row][col] + redsh[1][row][col] + redsh[2][row][col] + redsh[3][row][col];
    dec_part[kc*24576 + (mt*16 + row)*96 + col] = s;   // plain store, no atomic
  }
}

// ========== K6: 16-way partial sum + de-norm + output + aux ==========
__global__ __launch_bounds__(256) void k_final(const float* __restrict__ dec_part,
                                               const void* __restrict__ bh,
                                               int f32,
                                               const float* __restrict__ means,
                                               const float* __restrict__ stds,
                                               const float* __restrict__ sums,
                                               void* out){
  int o = blockIdx.x*256 + threadIdx.x;   // 0..24575
  int b = o / 3072, rem = o % 3072, j = rem >> 5, v = rem & 31;
  int bv = b*32 + v;
  int idx = bv*96 + j;
  float s = 0.f;
  #pragma unroll
  for (int kc = 0; kc < 16; ++kc) s += dec_part[kc*24576 + idx];
  float val = (s + ldin(bh, j, f32)) * stds[bv] + means[bv];
  stout(out, o, val, f32);
  if (o == 0){
    float bal = 0.f;
    for (int e = 0; e < 8; ++e) bal += (sums[e] / 16384.f) * (sums[8+e] / 16384.f);
    bal = 8.f * bal / 2.f;
    float aux = 0.01f * bal + 0.001f * (sums[16] / 16384.f);
    stout(out, 24576, aux, f32);
  }
}

extern "C" void kernel_launch(void* const* d_in, const int* in_sizes, int n_in,
                              void* d_out, int out_size, void* d_ws, size_t ws_size,
                              hipStream_t stream){
  const void* xe = d_in[0];
  const void* Wp = d_in[4];
  const void* Wg = d_in[5];
  const void* W1 = d_in[6];
  const void* b1 = d_in[7];
  const void* W2 = d_in[8];
  const void* b2 = d_in[9];
  const void* Wh = d_in[10];
  const void* bh = d_in[11];

  // dtype from input byte size: x_enc has 8*512*32 = 131072 elements.
  // bf16 -> 262144 B, f32 -> 524288 B. Default to f32 unless exact bf16 size.
  int f32 = 1;
  if (in_sizes && n_in > 0 && in_sizes[0] == 262144) f32 = 0;

  char* ws = (char*)d_ws;
  float* sums  = (float*)(ws + OFF_SUMS);
  float* means = (float*)(ws + OFF_MEANS);
  float* stds  = (float*)(ws + OFF_STDS);
  int*   ecnt  = (int*)(ws + OFF_ECNT);
  unsigned short* W1T   = (unsigned short*)(ws + OFF_W1T);
  unsigned short* W2T   = (unsigned short*)(ws + OFF_W2T);
  unsigned short* WhT   = (unsigned short*)(ws + OFF_WHT);
  float* cw    = (float*)(ws + OFF_CW);
  unsigned short* xfbf  = (unsigned short*)(ws + OFF_XFBF);
  unsigned short* flatb = (unsigned short*)(ws + OFF_FLATB);
  int*   elist = (int*)(ws + OFF_FLATB);   // overlay: dead before k_flat writes flatb
  float* Eo    = (float*)(ws + OFF_EO);
  int*   tokslot = (int*)(ws + OFF_TOKSLOT);
  float* dec_part = (float*)(ws + OFF_DECP);

  hipMemsetAsync(ws, 0, 3328, stream);                     // sums/ecnt header only
  k_prep_tr<<<1792, 256, 0, stream>>>(W1, W2, Wh, f32, W1T, W2T, WhT);
  k_embed<<<256, 256, 0, stream>>>(xe, Wp, Wg, f32, means, stds,
                                   xfbf, cw, sums, ecnt, elist, tokslot);
  k_moe<<<1032, 256, 0, stream>>>(xfbf, W1T, W2T, b1, f32, cw, ecnt, elist, Eo);
  k_flat<<<256, 256, 0, stream>>>(Eo, tokslot, cw, b2, f32, flatb);
  k_head<<<256, 256, 0, stream>>>(flatb, WhT, dec_part);
  k_final<<<96, 256, 0, stream>>>(dec_part, bh, f32, means, stds, sums, d_out);
}

// Round 14
// 153.323 us; speedup vs baseline: 1.0684x; 1.0684x over previous
//
#include <hip/hip_runtime.h>
#include <math.h>

// R17: byte-exact R12 (best measured, 157.3us) + ONE subtraction: the 3.3KB
// header memset is folded into k_prep_tr block 0 (which already runs first,
// computing only the small PE table) -- removes one dispatch from the graph.
// Consolidation rationale: R11/R13/R14/R15/R16 k_moe restructurings ALL lost
// to R12's wave-private ds_write-anchored hc-loop (rematerialization, VGPR
// pressure, bank conflicts, dependent-load exposure respectively); R12 is the
// compiler-stable local optimum. Remaining budget: ~84us harness ws-poison
// (untouchable) + ~73us ours, k_moe ~40us latency-bound.
// Pipeline: k_prep_tr(1793: hdr-zero+PE in blk0, transposes 1..1792)
// -> k_embed(256) -> k_moe(768, tile-stride over 1032) -> k_flat(256)
// -> k_head(256) -> k_final(96)

typedef __attribute__((ext_vector_type(8))) short bf16x8;
typedef __attribute__((ext_vector_type(4))) float f32x4;

__device__ __forceinline__ float bf2f(unsigned short u){
  unsigned x = ((unsigned)u) << 16; float f; __builtin_memcpy(&f, &x, 4); return f;
}
__device__ __forceinline__ unsigned short f2bf(float f){
  unsigned x; __builtin_memcpy(&x, &f, 4);
  return (unsigned short)((x + 0x7FFFu + ((x >> 16) & 1u)) >> 16);
}
__device__ __forceinline__ float ldin(const void* p, int i, int f32){
  return f32 ? ((const float*)p)[i] : bf2f(((const unsigned short*)p)[i]);
}
__device__ __forceinline__ void stout(void* p, int i, float v, int f32){
  if (f32) ((float*)p)[i] = v; else ((unsigned short*)p)[i] = f2bf(v);
}
__device__ __forceinline__ f32x4 mfma16(bf16x8 a, bf16x8 b, f32x4 c){
  return __builtin_amdgcn_mfma_f32_16x16x32_bf16(a, b, c, 0, 0, 0);
}
// raw barrier: waits only LDS ops, leaves global loads in flight (vs __syncthreads)
#define BAR_RAW() asm volatile("s_waitcnt lgkmcnt(0)\n\ts_barrier" ::: "memory")
// tanh-form gelu: x * sigmoid(1.5957691216*(x + 0.044715 x^3)); |dev vs erf-gelu| <~3e-4
__device__ __forceinline__ float gelu_fast(float v){
  float u = v*v;
  float inner = v * fmaf(0.044715f, u, 1.0f);
  float e = __expf(-1.5957691216f * inner);
  return v / (1.0f + e);     // v * sigmoid; e=inf -> 0, e=0 -> v  (no NaN)
}

// ---- ws layout (~82 MB of the 256 MiB workspace) ----
#define OFF_SUMS   64
#define OFF_MEANS  256
#define OFF_STDS   1280
#define OFF_ECNT   2304        // 8 expert counters @ 128B stride (ecnt[e*32]); hdr-zero 0..3328
#define OFF_PE     3328        // 8192 f32 (fully written by k_prep_tr block 0)
#define OFF_W1T    134400      // 8*512*128 bf16
#define OFF_W2T    1182976     // 8*128*512 bf16
#define OFF_WHT    2231552     // 96*8192 bf16
#define OFF_CW     3804416     // 16384*8 f32
#define OFF_XFBF   4328704     // 16384*128 bf16
#define OFF_FLATB  8523008     // 256*8192 bf16; elist (8*16384 int) overlays until k_flat
#define OFF_EO     12717312    // 8*16384 slots x 128 f32 = 64MB (sparse-used, no memset)
#define OFF_TOKSLOT 79826176   // 16384 x 2 int
#define OFF_DECP   79957248    // 16 x 24576 f32 partials (fully written by k_head)
// end ~81.5MB

// ========== K1: header zero + PE table (block 0) + tiled weight transposes ==========
__global__ __launch_bounds__(256) void k_prep_tr(const void* __restrict__ W1,
                                                 const void* __restrict__ W2,
                                                 const void* __restrict__ Wh,
                                                 int f32, int* hdr, float* pe,
                                                 unsigned short* W1T, unsigned short* W2T,
                                                 unsigned short* WhT){
  int t = threadIdx.x;
  if (blockIdx.x == 0){
    // zero the 3328B header (sums/ecnt) -- replaces the hipMemsetAsync dispatch;
    // k_prep_tr fully completes before k_embed (stream order), so safe.
    #pragma unroll
    for (int j = 0; j < 4; ++j){
      int i = j*256 + t;
      if (i < 832) hdr[i] = 0;
    }
    for (int i = t; i < 8192; i += 256){
      int p = i >> 7, d = i & 127;
      float freq = __expf(-(float)(d & ~1) * 0.07195578415606394f);
      float ang = (float)p * freq;
      pe[i] = (d & 1) ? __cosf(ang) : __sinf(ang);
    }
    return;
  }
  __shared__ float tile[32*33];
  int tb = blockIdx.x - 1;
  int r = t >> 3, cg = (t & 7) * 4;
  const void* src; unsigned short* dst;
  int in0, instride, out0, outstride;
  if (tb < 512){            // W1 [e][d 128][h 512] -> W1T [e][h][d]
    int e = tb >> 6, ti = tb & 63, d0 = (ti & 3) * 32, h0 = (ti >> 2) * 32;
    src = W1; dst = W1T;
    in0 = e*65536 + d0*512 + h0; instride = 512;
    out0 = e*65536 + h0*128 + d0; outstride = 128;
  } else if (tb < 1024){    // W2 [e][h 512][d 128] -> W2T [e][d][h]
    int tc = tb - 512;
    int e = tc >> 6, ti = tc & 63, d0 = (ti & 3) * 32, h0 = (ti >> 2) * 32;
    src = W2; dst = W2T;
    in0 = e*65536 + h0*128 + d0; instride = 128;
    out0 = e*65536 + d0*512 + h0; outstride = 512;
  } else {                  // Wh [k 8192][n 96] -> WhT [n][k]
    int tc = tb - 1024;
    int kt = tc / 3, nt = tc - kt*3;
    int k0 = kt*32, n0 = nt*32;
    src = Wh; dst = WhT;
    in0 = k0*96 + n0; instride = 96;
    out0 = n0*8192 + k0; outstride = 8192;
  }
  #pragma unroll
  for (int j = 0; j < 4; ++j)
    tile[r*33 + cg + j] = ldin(src, in0 + r*instride + cg + j, f32);
  __syncthreads();
  ushort4 o;
  o.x = f2bf(tile[(cg+0)*33 + r]);
  o.y = f2bf(tile[(cg+1)*33 + r]);
  o.z = f2bf(tile[(cg+2)*33 + r]);
  o.w = f2bf(tile[(cg+3)*33 + r]);
  *(ushort4*)(dst + out0 + r*outstride + cg) = o;
}

// ========== K2: per-bv stats + patch embed + PE + gating + aux + routing ==========
__global__ __launch_bounds__(256) void k_embed(const void* __restrict__ xe,
                                               const void* __restrict__ Wp,
                                               const void* __restrict__ Wg,
                                               int f32,
                                               const float* __restrict__ peg,
                                               float* means, float* stds,
                                               unsigned short* xfbf, float* cwg,
                                               float* sums,
                                               int* ecnt, int* elist, int* tokslot){
  __shared__ float xn[512];
  __shared__ float WpL[2048];
  __shared__ float WgL[1024];
  __shared__ float Xf[8192];
  __shared__ float lp[1024];
  __shared__ float taux[576];
  __shared__ float reds[256], redss[256];
  __shared__ float msh[2];
  __shared__ int lcnt[8], lbase[8];

  int bv = blockIdx.x;
  int b = bv >> 5, v = bv & 31;
  int t = threadIdx.x;

  if (t < 8) lcnt[t] = 0;

  float x0 = ldin(xe, (b*512 + t)*32 + v, f32);
  float x1 = ldin(xe, (b*512 + t + 256)*32 + v, f32);
  xn[t] = x0; xn[t+256] = x1;
  reds[t] = x0 + x1; redss[t] = x0*x0 + x1*x1;
  #pragma unroll
  for (int it = 0; it < 8; ++it)
    WpL[it*256 + t] = ldin(Wp, it*256 + t, f32);
  #pragma unroll
  for (int j = 0; j < 4; ++j)
    WgL[j*256 + t] = ldin(Wg, j*256 + t, f32);
  __syncthreads();
  for (int s = 128; s > 0; s >>= 1){
    if (t < s){ reds[t] += reds[t+s]; redss[t] += redss[t+s]; }
    __syncthreads();
  }
  if (t == 0){
    float m = reds[0] / 512.f;
    float sd = sqrtf(redss[0] / 512.f - m*m + 1e-5f);
    msh[0] = m; msh[1] = 1.f / sd;
    means[bv] = m; stds[bv] = sd;
  }
  __syncthreads();
  float mean = msh[0], rstd = msh[1];
  xn[t] = (xn[t] - mean) * rstd;
  xn[t+256] = (xn[t+256] - mean) * rstd;
  __syncthreads();
  {
    int p = t >> 2, q = t & 3;
    float tv[16];
    #pragma unroll
    for (int l = 0; l < 16; ++l){
      int xi = p*8 + l; if (xi > 511) xi = 511;   // edge pad
      tv[l] = xn[xi];
    }
    for (int dd = 0; dd < 32; ++dd){
      int d = q*32 + dd;
      float acc = peg[p*128 + d];
      #pragma unroll
      for (int l = 0; l < 16; ++l) acc += tv[l] * WpL[l*128 + d];
      Xf[p*128 + d] = acc;
    }
  }
  __syncthreads();
  if (t < 128){
    int p = t >> 1, half = t & 1;
    float s[8] = {0,0,0,0,0,0,0,0};
    for (int d = half*64; d < half*64 + 64; ++d){
      float xv = Xf[p*128 + d];
      #pragma unroll
      for (int e = 0; e < 8; ++e) s[e] += xv * WgL[d*8 + e];
    }
    #pragma unroll
    for (int e = 0; e < 8; ++e) lp[(p*2 + half)*8 + e] = s[e];
  }
  __syncthreads();
  int bi = 0, si = 0, lo0 = 0, lo1 = 0;
  if (t < 64){
    int p = t;
    float lg[8];
    #pragma unroll
    for (int e = 0; e < 8; ++e) lg[e] = lp[(p*2)*8 + e] + lp[(p*2+1)*8 + e];
    float m = lg[0];
    #pragma unroll
    for (int e = 1; e < 8; ++e) m = fmaxf(m, lg[e]);
    float pr[8]; float se = 0.f;
    #pragma unroll
    for (int e = 0; e < 8; ++e){ pr[e] = __expf(lg[e] - m); se += pr[e]; }
    float inv = 1.f / se;
    float lse = m + logf(se);
    #pragma unroll
    for (int e = 0; e < 8; ++e) pr[e] *= inv;
    float best = -1.f;
    #pragma unroll
    for (int e = 0; e < 8; ++e) if (pr[e] > best){ best = pr[e]; bi = e; }
    float sec = -1.f;
    #pragma unroll
    for (int e = 0; e < 8; ++e) if (e != bi && pr[e] > sec){ sec = pr[e]; si = e; }
    #pragma unroll
    for (int e = 0; e < 8; ++e){
      float w = (e == bi) ? best : ((e == si) ? sec : 0.f);
      cwg[(bv*64 + p)*8 + e] = w;
      taux[p*9 + e] = pr[e];
    }
    taux[p*9 + 8] = lse * lse;
    lp[p] = (float)bi; lp[64 + p] = (float)si;   // reuse lp for mask info
    // --- routing: fast LDS atomics give local offsets (order-free) ---
    lo0 = atomicAdd(&lcnt[bi], 1);
    lo1 = atomicAdd(&lcnt[si], 1);
  }
  __syncthreads();
  // one global atomic per (block, expert); counters 128B apart -> parallel lines
  if (t < 8) lbase[t] = atomicAdd(ecnt + t*32, lcnt[t]);
  __syncthreads();
  if (t < 64){
    int n = bv*64 + t;
    int p0 = lbase[bi] + lo0, p1 = lbase[si] + lo1;
    elist[bi*16384 + p0] = n;
    elist[si*16384 + p1] = n;
    tokslot[n*2]     = (bi << 14) + p0;    // slot = e*16384 + pos
    tokslot[n*2 + 1] = (si << 14) + p1;
  }
  if (t < 17){
    float s = 0.f;
    if (t < 8){ for (int p = 0; p < 64; ++p) s += taux[p*9 + t]; }
    else if (t < 16){
      int e = t - 8;
      for (int p = 0; p < 64; ++p)
        s += ((int)lp[p] == e || (int)lp[64+p] == e) ? 1.f : 0.f;
    }
    else { for (int p = 0; p < 64; ++p) s += taux[p*9 + 8]; }
    atomicAdd(sums + t, s);
  }
  // Xf -> bf16 xfbf (coalesced b128)
  #pragma unroll
  for (int pass = 0; pass < 4; ++pass){
    int idx = pass*256 + t;         // 1024 groups of 8
    int base = idx*8;
    bf16x8 o;
    #pragma unroll
    for (int j = 0; j < 8; ++j) o[j] = (short)f2bf(Xf[base + j]);
    *(bf16x8*)(xfbf + bv*8192 + base) = o;
  }
}

// ========== K3: routed top-2 FFN, wave-private LDS staging, raw barriers, tile-stride ==========
// grid = 768; block b processes tiles b and b+768 (total tiles <= 1032).
__global__ __launch_bounds__(256, 3) void k_moe(const unsigned short* __restrict__ xfbf,
                                                const unsigned short* __restrict__ W1T,
                                                const unsigned short* __restrict__ W2T,
                                                const void* __restrict__ b1g,
                                                int f32,
                                                const float* __restrict__ cwg,
                                                const int* __restrict__ ecnt,
                                                const int* __restrict__ elist,
                                                float* __restrict__ Eo){
  __shared__ __align__(16) char lds[49664];
  short* Xs  = (short*)(lds);            // [32][136] gathered tokens  (8704B)
  short* Bu1 = (short*)(lds + 8704);     // [64][136]: wave w owns rows [16w,16w+16)
  short* Bu2 = (short*)(lds + 26112);    // [128][72]: wave w owns rows [32w,32w+32)
  short* Ag  = (short*)(lds + 44544);    // [32][72] gelu out (cross-wave)
  float* cws = (float*)(lds + 49152);    // [32]
  int*   lsn = (int*)(lds + 49280);      // [32] routed token ids

  int t = threadIdx.x;
  int wave = t >> 6, lane = t & 63;
  int quad = lane >> 4, li = lane & 15;
  int c1 = wave * 16;                    // GEMM1 column (h) slice per wave
  int c2 = wave * 32;                    // GEMM2 column (d) slice per wave

  for (int tb = blockIdx.x; tb < 1536; tb += 768){
    // map tile index -> (expert e, tile ti) via redundant prefix over 8 counters
    int e = 8, ti = 0;
    {
      int acc = 0;
      #pragma unroll
      for (int ee = 0; ee < 8; ++ee){
        int tl = (ecnt[ee*32] + 31) >> 5;
        if (e == 8 && tb < acc + tl){ e = ee; ti = tb - acc; }
        acc += tl;
      }
    }
    if (e == 8) break;                   // past total tiles (block-uniform)
    int cntE = ecnt[e*32];
    int tbase = ti*32;

    const unsigned short* W1e = W1T + e*65536;
    const unsigned short* W2e = W2T + e*65536;

    // ---- issue hc=0 wave-private weight loads first (fly under routing+gather)
    bf16x8 pf1[4], pf2[4];
    #pragma unroll
    for (int pass = 0; pass < 4; ++pass){
      int idx = pass*64 + lane;
      int row = idx >> 4, kg = idx & 15;   // 16 rows x 16 kg
      pf1[pass] = *(const bf16x8*)(W1e + (c1 + row)*128 + kg*8);
    }
    #pragma unroll
    for (int pass = 0; pass < 4; ++pass){
      int idx = pass*64 + lane;
      int row = idx >> 3, kg = idx & 7;    // 32 rows x 8 kg
      pf2[pass] = *(const bf16x8*)(W2e + (c2 + row)*512 + kg*8);
    }

    if (t < 32){
      int ok = (tbase + t) < cntE;
      int n = ok ? elist[e*16384 + tbase + t] : 0;
      lsn[t] = n;
      cws[t] = ok ? cwg[n*8 + e] : 0.f;    // cw=0 pads -> zero contribution
    }
    __syncthreads();   // rendezvous: prev tile fully consumed; lsn/cws visible
    // gather 32 token rows (512 x b128)
    #pragma unroll
    for (int pass = 0; pass < 2; ++pass){
      int idx = pass*256 + t;
      int row = idx >> 4, kg = idx & 15;
      int n = lsn[row];
      *(bf16x8*)(Xs + row*136 + kg*8) =
        *(const bf16x8*)(xfbf + n*128 + kg*8);
    }
    // per-lane gate weights for the 8 rows this lane touches
    float cwv[2][4];
    #pragma unroll
    for (int rt = 0; rt < 2; ++rt)
      #pragma unroll
      for (int r = 0; r < 4; ++r)
        cwv[rt][r] = cws[rt*16 + quad*4 + r];
    __syncthreads();                       // Xs visible (drains pf0 once/tile; acceptable)

    f32x4 Yacc[2][2];
    #pragma unroll
    for (int a = 0; a < 2; ++a)
      #pragma unroll
      for (int bb = 0; bb < 2; ++bb){ f32x4 z = {0.f,0.f,0.f,0.f}; Yacc[a][bb] = z; }

    for (int hc = 0; hc < 8; ++hc){
      // 1. stage OWN slices from pf regs (same-wave RAW -> lgkmcnt only, no barrier)
      #pragma unroll
      for (int pass = 0; pass < 4; ++pass){
        int idx = pass*64 + lane;
        int row = idx >> 4, kg = idx & 15;
        *(bf16x8*)(Bu1 + (c1 + row)*136 + kg*8) = pf1[pass];
      }
      #pragma unroll
      for (int pass = 0; pass < 4; ++pass){
        int idx = pass*64 + lane;
        int row = idx >> 3, kg = idx & 7;
        *(bf16x8*)(Bu2 + (c2 + row)*72 + kg*8) = pf2[pass];
      }
      // 2. bias load BEFORE pf issue: its use waits vmcnt(8), keeping pf in flight
      float bias = ldin(b1g, e*512 + hc*64 + c1 + li, f32);
      // 3. issue next chunk's wave-private loads (stay in flight across raw barriers)
      if (hc < 7){
        #pragma unroll
        for (int pass = 0; pass < 4; ++pass){
          int idx = pass*64 + lane;
          int row = idx >> 4, kg = idx & 15;
          pf1[pass] = *(const bf16x8*)(W1e + ((hc+1)*64 + c1 + row)*128 + kg*8);
        }
        #pragma unroll
        for (int pass = 0; pass < 4; ++pass){
          int idx = pass*64 + lane;
          int row = idx >> 3, kg = idx & 7;
          pf2[pass] = *(const bf16x8*)(W2e + (c2 + row)*512 + (hc+1)*64 + kg*8);
        }
      }
      // 4. GEMM1: 32 tok x 16 h per wave, K=128 (own Bu1 slice)
      f32x4 acc1[2];
      { f32x4 z = {0.f,0.f,0.f,0.f}; acc1[0] = z; acc1[1] = z; }
      #pragma unroll
      for (int ks = 0; ks < 4; ++ks){
        int kk = ks*32 + quad*8;
        bf16x8 a0 = *(const bf16x8*)(Xs + li*136 + kk);
        bf16x8 a1 = *(const bf16x8*)(Xs + (16 + li)*136 + kk);
        bf16x8 b0 = *(const bf16x8*)(Bu1 + (c1 + li)*136 + kk);
        acc1[0] = mfma16(a0, b0, acc1[0]);
        acc1[1] = mfma16(a1, b0, acc1[1]);
      }
      // 5. barrier A: all waves' prev-iter Ag reads retired (LDS-only wait)
      BAR_RAW();
      // 6. gelu -> Ag (own cols, all rows)
      #pragma unroll
      for (int rt = 0; rt < 2; ++rt){
        #pragma unroll
        for (int r = 0; r < 4; ++r){
          int row = rt*16 + quad*4 + r;
          float g = gelu_fast(acc1[rt][r] + bias);
          Ag[row*72 + c1 + li] = (short)f2bf(g * cwv[rt][r]);
        }
      }
      // 7. barrier B: Ag writes visible (lgkmcnt(0) + s_barrier; vmcnt untouched)
      BAR_RAW();
      // 8. GEMM2: 32 tok x 32 d per wave, K=64 (Ag all cols + own Bu2 slice)
      #pragma unroll
      for (int ks = 0; ks < 2; ++ks){
        int kk = ks*32 + quad*8;
        bf16x8 a0 = *(const bf16x8*)(Ag + li*72 + kk);
        bf16x8 a1 = *(const bf16x8*)(Ag + (16 + li)*72 + kk);
        #pragma unroll
        for (int ct = 0; ct < 2; ++ct){
          bf16x8 bb = *(const bf16x8*)(Bu2 + (c2 + ct*16 + li)*72 + kk);
          Yacc[0][ct] = mfma16(a0, bb, Yacc[0][ct]);
          Yacc[1][ct] = mfma16(a1, bb, Yacc[1][ct]);
        }
      }
    }
    // epilogue: plain stores to this pair's private slot rows (no atomics)
    #pragma unroll
    for (int ct = 0; ct < 2; ++ct){
      int col = c2 + ct*16 + li;
      #pragma unroll
      for (int rt = 0; rt < 2; ++rt)
        #pragma unroll
        for (int r = 0; r < 4; ++r){
          int row = rt*16 + quad*4 + r;
          if (tbase + row < cntE)
            Eo[(size_t)((e << 14) + tbase + row)*128 + col] = Yacc[rt][ct][r];
        }
    }
  }
}

// ========== K4: Eo slot gather-add + sum_e cw*b2 -> flat bf16 [bv][d*64+p] ==========
__global__ __launch_bounds__(256) void k_flat(const float* __restrict__ Eo,
                                              const int* __restrict__ tokslot,
                                              const float* __restrict__ cwg,
                                              const void* __restrict__ b2g,
                                              int f32,
                                              unsigned short* __restrict__ flatb){
  __shared__ float Yl[64*130];
  __shared__ float b2f[1024];
  __shared__ float cwl[512];
  __shared__ int tsl[128];
  int bv = blockIdx.x;
  int t = threadIdx.x;
  if (t < 64){
    int2 v = *(const int2*)(tokslot + (bv*64 + t)*2);
    tsl[t*2] = v.x; tsl[t*2+1] = v.y;
  }
  #pragma unroll
  for (int j = 0; j < 4; ++j) b2f[j*256 + t] = ldin(b2g, j*256 + t, f32);
  #pragma unroll
  for (int j = 0; j < 2; ++j) cwl[j*256 + t] = cwg[bv*512 + j*256 + t];
  __syncthreads();
  #pragma unroll
  for (int pass = 0; pass < 32; ++pass){
    int idx = pass*256 + t;
    int row = idx >> 7, col = idx & 127;
    Yl[row*130 + col] = Eo[(size_t)tsl[row*2]*128 + col]
                      + Eo[(size_t)tsl[row*2+1]*128 + col];
  }
  __syncthreads();
  int d = t >> 1, ph = (t & 1) * 32;
  float b2c[8];
  #pragma unroll
  for (int e = 0; e < 8; ++e) b2c[e] = b2f[e*128 + d];
  unsigned short ob[32];
  for (int j = 0; j < 32; ++j){
    int p = ph + j;
    float add = 0.f;
    #pragma unroll
    for (int e = 0; e < 8; ++e) add += cwl[p*8 + e] * b2c[e];
    ob[j] = f2bf(Yl[p*130 + d] + add);
  }
  #pragma unroll
  for (int m = 0; m < 4; ++m)
    *(bf16x8*)(flatb + bv*8192 + d*64 + ph + m*8) = *(bf16x8*)(ob + m*8);
}

// ========== K5: head GEMM (M=256, N=96, K=8192; K-split 16, partial stores) ==========
__global__ __launch_bounds__(256) void k_head(const unsigned short* __restrict__ flatb,
                                              const unsigned short* __restrict__ WhT,
                                              float* __restrict__ dec_part){
  int t = threadIdx.x;
  int mt = blockIdx.x & 15, kc = blockIdx.x >> 4;
  int wave = t >> 6, lane = t & 63, quad = lane >> 4, li = lane & 15;
  int kbase = kc*512 + wave*128;
  f32x4 acc[6];
  #pragma unroll
  for (int nt = 0; nt < 6; ++nt){ f32x4 z = {0.f,0.f,0.f,0.f}; acc[nt] = z; }
  #pragma unroll
  for (int ks = 0; ks < 4; ++ks){
    int k = kbase + ks*32 + quad*8;
    bf16x8 a = *(const bf16x8*)(flatb + (mt*16 + li)*8192 + k);
    #pragma unroll
    for (int nt = 0; nt < 6; ++nt){
      bf16x8 b = *(const bf16x8*)(WhT + (nt*16 + li)*8192 + k);
      acc[nt] = mfma16(a, b, acc[nt]);
    }
  }
  __shared__ float redsh[4][16][96];
  #pragma unroll
  for (int nt = 0; nt < 6; ++nt)
    #pragma unroll
    for (int r = 0; r < 4; ++r)
      redsh[wave][quad*4 + r][nt*16 + li] = acc[nt][r];
  __syncthreads();
  #pragma unroll
  for (int u = 0; u < 6; ++u){
    int o = t*6 + u;
    int row = o / 96, col = o % 96;
    float s = redsh[0][row][col] + redsh[1][row][col] + redsh[2][row][col] + redsh[3][row][col];
    dec_part[kc*24576 + (mt*16 + row)*96 + col] = s;   // plain store, no atomic
  }
}

// ========== K6: 16-way partial sum + de-norm + output + aux ==========
__global__ __launch_bounds__(256) void k_final(const float* __restrict__ dec_part,
                                               const void* __restrict__ bh,
                                               int f32,
                                               const float* __restrict__ means,
                                               const float* __restrict__ stds,
                                               const float* __restrict__ sums,
                                               void* out){
  int o = blockIdx.x*256 + threadIdx.x;   // 0..24575
  int b = o / 3072, rem = o % 3072, j = rem >> 5, v = rem & 31;
  int bv = b*32 + v;
  int idx = bv*96 + j;
  float s = 0.f;
  #pragma unroll
  for (int kc = 0; kc < 16; ++kc) s += dec_part[kc*24576 + idx];
  float val = (s + ldin(bh, j, f32)) * stds[bv] + means[bv];
  stout(out, o, val, f32);
  if (o == 0){
    float bal = 0.f;
    for (int e = 0; e < 8; ++e) bal += (sums[e] / 16384.f) * (sums[8+e] / 16384.f);
    bal = 8.f * bal / 2.f;
    float aux = 0.01f * bal + 0.001f * (sums[16] / 16384.f);
    stout(out, 24576, aux, f32);
  }
}

extern "C" void kernel_launch(void* const* d_in, const int* in_sizes, int n_in,
                              void* d_out, int out_size, void* d_ws, size_t ws_size,
                              hipStream_t stream){
  const void* xe = d_in[0];
  const void* Wp = d_in[4];
  const void* Wg = d_in[5];
  const void* W1 = d_in[6];
  const void* b1 = d_in[7];
  const void* W2 = d_in[8];
  const void* b2 = d_in[9];
  const void* Wh = d_in[10];
  const void* bh = d_in[11];

  // dtype from input byte size: x_enc has 8*512*32 = 131072 elements.
  // bf16 -> 262144 B, f32 -> 524288 B. Default to f32 unless exact bf16 size.
  int f32 = 1;
  if (in_sizes && n_in > 0 && in_sizes[0] == 262144) f32 = 0;

  char* ws = (char*)d_ws;
  int*   hdr   = (int*)ws;
  float* sums  = (float*)(ws + OFF_SUMS);
  float* means = (float*)(ws + OFF_MEANS);
  float* stds  = (float*)(ws + OFF_STDS);
  int*   ecnt  = (int*)(ws + OFF_ECNT);
  float* pe    = (float*)(ws + OFF_PE);
  unsigned short* W1T   = (unsigned short*)(ws + OFF_W1T);
  unsigned short* W2T   = (unsigned short*)(ws + OFF_W2T);
  unsigned short* WhT   = (unsigned short*)(ws + OFF_WHT);
  float* cw    = (float*)(ws + OFF_CW);
  unsigned short* xfbf  = (unsigned short*)(ws + OFF_XFBF);
  unsigned short* flatb = (unsigned short*)(ws + OFF_FLATB);
  int*   elist = (int*)(ws + OFF_FLATB);   // overlay: dead before k_flat writes flatb
  float* Eo    = (float*)(ws + OFF_EO);
  int*   tokslot = (int*)(ws + OFF_TOKSLOT);
  float* dec_part = (float*)(ws + OFF_DECP);

  k_prep_tr<<<1793, 256, 0, stream>>>(W1, W2, Wh, f32, hdr, pe, W1T, W2T, WhT);
  k_embed<<<256, 256, 0, stream>>>(xe, Wp, Wg, f32, pe, means, stds,
                                   xfbf, cw, sums, ecnt, elist, tokslot);
  k_moe<<<768, 256, 0, stream>>>(xfbf, W1T, W2T, b1, f32, cw, ecnt, elist, Eo);
  k_flat<<<256, 256, 0, stream>>>(Eo, tokslot, cw, b2, f32, flatb);
  k_head<<<256, 256, 0, stream>>>(flatb, WhT, dec_part);
  k_final<<<96, 256, 0, stream>>>(dec_part, bh, f32, means, stds, sums, d_out);
}